// Round 1
// baseline (1944.495 us; speedup 1.0000x reference)
//
#include <hip/hip_runtime.h>
#include <cstdint>
#include <cstddef>

// ---------------- gather x0 = emb[node_ids] ----------------
__global__ void gather_x0_k(const int* __restrict__ nid, const float* __restrict__ emb,
                            float* __restrict__ x0, int N) {
    int i = blockIdx.x * blockDim.x + threadIdx.x;
    int n = i >> 5;                 // 32 threads per row (128 floats / float4)
    if (n >= N) return;
    int c = (i & 31) << 2;
    int s = nid[n];
    float4 v = *reinterpret_cast<const float4*>(emb + (size_t)s * 128 + c);
    *reinterpret_cast<float4*>(x0 + (size_t)n * 128 + c) = v;
}

// ---------------- CSR build: histogram ----------------
__global__ void hist_k(const int* __restrict__ erow, int* __restrict__ counts, int E) {
    int e = blockIdx.x * blockDim.x + threadIdx.x;
    if (e < E) atomicAdd(&counts[erow[e]], 1);
}

// ---------------- scan pass 1: per-block (1024 elems) exclusive scan ----------------
__global__ void scan1_k(const int* __restrict__ counts, int* __restrict__ rs,
                        int* __restrict__ bsum, int n) {
    __shared__ int ts[256];
    int tid = threadIdx.x;
    int idx = blockIdx.x * 1024 + tid * 4;
    int v0 = (idx + 0 < n) ? counts[idx + 0] : 0;
    int v1 = (idx + 1 < n) ? counts[idx + 1] : 0;
    int v2 = (idx + 2 < n) ? counts[idx + 2] : 0;
    int v3 = (idx + 3 < n) ? counts[idx + 3] : 0;
    int local = v0 + v1 + v2 + v3;
    ts[tid] = local;
    __syncthreads();
    for (int off = 1; off < 256; off <<= 1) {
        int t = (tid >= off) ? ts[tid - off] : 0;
        __syncthreads();
        ts[tid] += t;
        __syncthreads();
    }
    if (tid == 255) bsum[blockIdx.x] = ts[255];
    int run = ts[tid] - local;   // exclusive prefix of this thread's quad
    if (idx + 0 < n) rs[idx + 0] = run; run += v0;
    if (idx + 1 < n) rs[idx + 1] = run; run += v1;
    if (idx + 2 < n) rs[idx + 2] = run; run += v2;
    if (idx + 3 < n) rs[idx + 3] = run;
}

// ---------------- scan pass 2: exclusive scan of block sums (nb <= 256) ----------------
__global__ void scan2_k(int* __restrict__ bsum, int nb) {
    __shared__ int ts[256];
    int tid = threadIdx.x;
    int v = (tid < nb) ? bsum[tid] : 0;
    ts[tid] = v;
    __syncthreads();
    for (int off = 1; off < 256; off <<= 1) {
        int t = (tid >= off) ? ts[tid - off] : 0;
        __syncthreads();
        ts[tid] += t;
        __syncthreads();
    }
    if (tid < nb) bsum[tid] = ts[tid] - v;
}

// ---------------- scan pass 3: add block offsets, init cursor, set rs[n]=E ----------------
__global__ void scan3_k(int* __restrict__ rs, const int* __restrict__ bsum,
                        int* __restrict__ cursor, int n, int E) {
    int idx = blockIdx.x * blockDim.x + threadIdx.x;
    if (idx < n) {
        int v = rs[idx] + bsum[idx >> 10];
        rs[idx] = v;
        cursor[idx] = v;
    } else if (idx == n) {
        rs[n] = E;
    }
}

// ---------------- counting-sort scatter into (col, val) pairs ----------------
__global__ void scatter_k(const int* __restrict__ erow, const int* __restrict__ ecol,
                          const float* __restrict__ eval, int* __restrict__ cursor,
                          uint2* __restrict__ cv, int E) {
    int e = blockIdx.x * blockDim.x + threadIdx.x;
    if (e >= E) return;
    int r = erow[e];
    int pos = atomicAdd(&cursor[r], 1);
    cv[pos] = make_uint2((unsigned)ecol[e], __float_as_uint(eval[e]));
}

// ---------------- SpMM: one wave per output row, register accumulation ----------------
__global__ void spmm_k(const int* __restrict__ rs, const uint2* __restrict__ cv,
                       const float* __restrict__ x, float* __restrict__ agg, int N) {
    int gw = (blockIdx.x * blockDim.x + threadIdx.x) >> 6;   // global wave id = row
    if (gw >= N) return;
    int lane = threadIdx.x & 63;
    int s = __builtin_amdgcn_readfirstlane(rs[gw]);
    int e = __builtin_amdgcn_readfirstlane(rs[gw + 1]);
    int d0 = lane << 1;                                      // 2 columns per lane
    const float* xb = x + d0;
    float ax0 = 0.f, ay0 = 0.f, ax1 = 0.f, ay1 = 0.f;
    int k = s;
    for (; k + 1 < e; k += 2) {                              // 2-deep to expose MLP
        uint2 p0 = cv[k];
        uint2 p1 = cv[k + 1];
        float v0 = __uint_as_float(p0.y);
        float v1 = __uint_as_float(p1.y);
        float2 r0 = *reinterpret_cast<const float2*>(xb + (size_t)p0.x * 128);
        float2 r1 = *reinterpret_cast<const float2*>(xb + (size_t)p1.x * 128);
        ax0 = fmaf(v0, r0.x, ax0); ay0 = fmaf(v0, r0.y, ay0);
        ax1 = fmaf(v1, r1.x, ax1); ay1 = fmaf(v1, r1.y, ay1);
    }
    if (k < e) {
        uint2 p0 = cv[k];
        float v0 = __uint_as_float(p0.y);
        float2 r0 = *reinterpret_cast<const float2*>(xb + (size_t)p0.x * 128);
        ax0 = fmaf(v0, r0.x, ax0); ay0 = fmaf(v0, r0.y, ay0);
    }
    float2 o; o.x = ax0 + ax1; o.y = ay0 + ay1;
    *reinterpret_cast<float2*>(agg + (size_t)gw * 128 + d0) = o;
}

// ---------------- dense: out = relu(agg @ W + b), W columns held in VGPRs ----------------
#define DB_ROWS 8
__global__ __launch_bounds__(256) void dense_k(const float* __restrict__ agg,
                                               const float* __restrict__ W,
                                               const float* __restrict__ b,
                                               float* __restrict__ out, int N) {
    __shared__ float arow[DB_ROWS][128];
    __shared__ float partial[DB_ROWS][128];
    int tid = threadIdx.x;
    int j = tid & 127;
    int half = tid >> 7;           // which half of k-range this thread owns
    float w[64];
#pragma unroll
    for (int i = 0; i < 64; ++i) w[i] = W[(size_t)(half * 64 + i) * 128 + j];
    float bj = b[j];

    for (int base = blockIdx.x * DB_ROWS; base < N; base += gridDim.x * DB_ROWS) {
        // stage up to 8 agg rows (zero-fill OOB rows)
        for (int idx = tid; idx < DB_ROWS * 128; idx += 256) {
            int rr = base + (idx >> 7);
            arow[idx >> 7][idx & 127] = (rr < N) ? agg[(size_t)rr * 128 + (idx & 127)] : 0.f;
        }
        __syncthreads();
        float acc[DB_ROWS];
#pragma unroll
        for (int r = 0; r < DB_ROWS; ++r) {
            float s = 0.f;
#pragma unroll
            for (int i = 0; i < 64; ++i) s = fmaf(arow[r][half * 64 + i], w[i], s);
            acc[r] = s;
        }
        __syncthreads();
        if (half == 1) {
#pragma unroll
            for (int r = 0; r < DB_ROWS; ++r) partial[r][j] = acc[r];
        }
        __syncthreads();
        if (half == 0) {
#pragma unroll
            for (int r = 0; r < DB_ROWS; ++r) {
                if (base + r < N) {
                    float v = acc[r] + partial[r][j] + bj;
                    out[(size_t)(base + r) * 128 + j] = fmaxf(v, 0.f);
                }
            }
        }
        __syncthreads();
    }
}

extern "C" void kernel_launch(void* const* d_in, const int* in_sizes, int n_in,
                              void* d_out, int out_size, void* d_ws, size_t ws_size,
                              hipStream_t stream) {
    const int*   nid  = (const int*)d_in[0];
    const int*   erow = (const int*)d_in[1];
    const int*   ecol = (const int*)d_in[2];
    const float* eval = (const float*)d_in[3];
    const float* emb  = (const float*)d_in[4];
    const float* W1   = (const float*)d_in[5];
    const float* b1   = (const float*)d_in[6];
    const float* W2   = (const float*)d_in[7];
    const float* b2   = (const float*)d_in[8];
    int N = in_sizes[0];
    int E = in_sizes[1];
    float* out = (float*)d_out;

    auto al = [](size_t x) { return (x + 255) & ~(size_t)255; };
    char* w = (char*)d_ws;
    int*   counts = (int*)w;   w += al((size_t)N * 4);
    int*   rs     = (int*)w;   w += al((size_t)(N + 1) * 4);
    int*   cursor = (int*)w;   w += al((size_t)N * 4);
    int*   bsum   = (int*)w;   w += al((size_t)1024 * 4);
    uint2* cv     = (uint2*)w; w += al((size_t)E * 8);
    float* agg    = (float*)w; w += al((size_t)N * 128 * 4);

    hipMemsetAsync(counts, 0, (size_t)N * 4, stream);

    // x0 = emb[node_ids]  -> stored in d_out (overwritten later)
    gather_x0_k<<<(N * 32 + 255) / 256, 256, 0, stream>>>(nid, emb, out, N);

    // CSR build
    int nb1 = (N + 1023) / 1024;
    hist_k<<<(E + 255) / 256, 256, 0, stream>>>(erow, counts, E);
    scan1_k<<<nb1, 256, 0, stream>>>(counts, rs, bsum, N);
    scan2_k<<<1, 256, 0, stream>>>(bsum, nb1);
    scan3_k<<<(N + 1 + 255) / 256, 256, 0, stream>>>(rs, bsum, cursor, N, E);
    scatter_k<<<(E + 255) / 256, 256, 0, stream>>>(erow, ecol, eval, cursor, cv, E);

    // layer 1:  agg = A @ x0 ; x1 = relu(agg@W1+b1) -> d_out
    spmm_k<<<(N + 3) / 4, 256, 0, stream>>>(rs, cv, out, agg, N);
    dense_k<<<2048, 256, 0, stream>>>(agg, W1, b1, out, N);

    // layer 2:  agg = A @ x1 ; out = relu(agg@W2+b2) -> d_out
    spmm_k<<<(N + 3) / 4, 256, 0, stream>>>(rs, cv, out, agg, N);
    dense_k<<<2048, 256, 0, stream>>>(agg, W2, b2, out, N);
}